// Round 11
// baseline (171.217 us; speedup 1.0000x reference)
//
#include <hip/hip_runtime.h>
#include <hip/hip_bf16.h>
#include <math.h>

#define NN     8192
#define FDIM   64
#define EDGES  262144
#define BATCH  2
#define ALPHA  0.2f

#define NB     256        // coarse buckets (src >> 5)
#define SRCB   32         // srcs per bucket
#define BCAP   1280       // mean 1024 + 8 sigma
#define ROWCAP 128        // per-src cap (Poisson(32): P(>128) negligible)

// ---- ws layout ----
#define OFF_WH    0u          // float[B*N*64]  4 MB
#define OFF_S1    4194304u    // float[B*N]     64 KB
#define OFF_S2    4259840u    // float[B*N]     64 KB
#define OFF_OFFS  4325376u    // u16[256][256]  128 KB  (offsT[g][chunk])
#define OFF_CRS   4456448u    // uint2[256*1024] 2 MB (chunk-private, bucket-sorted)
#define OFF_CEW   6553600u    // float[256*1024] 1 MB (edge weights, same order)

// K1: 256 blocks x 512 (8 waves). Bucket 1024 edges (2/thr, LDS hist+scan, no
// global atomics) + GEMM: 8 rows/wave, W streamed per-lane float4 (L1-resident
// 16 KB), h wave-uniform broadcast. ~60 live VGPRs -> no spill at 128 cap.
__global__ __launch_bounds__(512) void stage1_kernel(
    const float* __restrict__ h, const float* __restrict__ W,
    const float* __restrict__ a, const int* __restrict__ ei,
    const float* __restrict__ ew,
    float* __restrict__ Wh, float* __restrict__ s1g, float* __restrict__ s2g,
    unsigned short* __restrict__ offsT, uint2* __restrict__ coarse,
    float* __restrict__ cew) {
  __shared__ int hist[NB];
  __shared__ int offs[NB];
  int tid = threadIdx.x, lane = tid & 63, w = tid >> 6;
  int blk = blockIdx.x;

  // ---- bucket: 2 edges/thread, hist + rank (R8-proven) ----
  int e0 = blk * 1024 + tid, e1 = e0 + 512;
  int sa = ei[e0], da = ei[EDGES + e0];
  int sb = ei[e1], db = ei[EDGES + e1];
  int ga = sa >> 5, gb = sb >> 5;
  if (tid < NB) hist[tid] = 0;
  __syncthreads();
  int ra = atomicAdd(&hist[ga], 1);           // LDS atomics only
  int rb = atomicAdd(&hist[gb], 1);
  __syncthreads();
  if (tid < 64) {                             // wave 0: exclusive scan of 256
    int i0 = tid * 4;
    int c0 = hist[i0], c1 = hist[i0 + 1], c2 = hist[i0 + 2], c3 = hist[i0 + 3];
    int sum = c0 + c1 + c2 + c3;
    int x = sum;
#pragma unroll
    for (int off = 1; off < 64; off <<= 1) {
      int y = __shfl_up(x, off, 64);
      if (tid >= off) x += y;
    }
    int ex = x - sum;
    offs[i0] = ex; offs[i0 + 1] = ex + c0;
    offs[i0 + 2] = ex + c0 + c1; offs[i0 + 3] = ex + c0 + c1 + c2;
  }
  __syncthreads();
  float wa = ew[e0], wb = ew[e1];             // coalesced
  int pa = blk * 1024 + offs[ga] + ra;
  int pb = blk * 1024 + offs[gb] + rb;
  coarse[pa] = make_uint2(((unsigned)e0 << 13) | (unsigned)da, (unsigned)sa);
  coarse[pb] = make_uint2(((unsigned)e1 << 13) | (unsigned)db, (unsigned)sb);
  cew[pa] = wa;
  cew[pb] = wb;
  if (tid < NB) offsT[tid * 256 + blk] = (unsigned short)offs[tid];

  // ---- GEMM: 8 rows/wave; W per-lane float4 stream (L1-hot), h uniform ----
  int nn0 = blk * 64 + w * 8;                 // this wave's 8 rows in [0, B*N)
  const float4* W4 = (const float4*)(W + lane * 64);
  float acc[8] = {0.f, 0.f, 0.f, 0.f, 0.f, 0.f, 0.f, 0.f};
#pragma unroll
  for (int k4 = 0; k4 < 16; ++k4) {
    float4 wv = W4[k4];
#pragma unroll
    for (int r = 0; r < 8; ++r) {
      float4 hv = *((const float4*)(h + (size_t)(nn0 + r) * 64) + k4);  // uniform
      acc[r] += hv.x * wv.x + hv.y * wv.y + hv.z * wv.z + hv.w * wv.w;
    }
  }
  float a1 = a[lane], a2 = a[64 + lane];
#pragma unroll
  for (int r = 0; r < 8; ++r) {
    int nn = nn0 + r;
    Wh[(size_t)nn * 64 + lane] = acc[r];
    float p1 = acc[r] * a1, p2 = acc[r] * a2;
#pragma unroll
    for (int off = 32; off; off >>= 1) {
      p1 += __shfl_xor(p1, off, 64);
      p2 += __shfl_xor(p2, off, 64);
    }
    if (lane == 0) { s1g[nn] = p1; s2g[nn] = p2; }
  }
}

// K2: 512 blocks (B x NB) x 1024 thr. Merge 256 chunk segments, regroup by
// src in LDS, then per wave x2 rows: bitmap dup-detect (fastpath skips the
// O(deg) shuffle dedupe), masked softmax, 4-lane-per-edge float4 gather.
__global__ __launch_bounds__(1024) void stage2_kernel(
    const float* __restrict__ s1g, const float* __restrict__ s2g,
    const unsigned short* __restrict__ offsT, const uint2* __restrict__ coarse,
    const float* __restrict__ cew, const float* __restrict__ Wh,
    float* __restrict__ out) {
  __shared__ uint2 grp[BCAP];
  __shared__ int dstBase[257];
  __shared__ int srcPos[256];
  __shared__ int rhist[SRCB];
  __shared__ int roffs[SRCB];
  __shared__ float s1loc[SRCB];
  __shared__ unsigned bmap[16 * 256];          // per-wave 8192-bit dst bitmap
  int tid = threadIdx.x, lane = tid & 63, w = tid >> 6;   // 16 waves
  int blk = blockIdx.x;
  int xcd = blk & 7;
  int b = xcd >> 2;                            // XCD 0-3: batch 0, 4-7: batch 1
  int g = (blk >> 3) * 4 + (xcd & 3);          // [0, 256)
  const float* s2b = s2g + b * NN;
  if (tid < SRCB) {
    rhist[tid] = 0;
    s1loc[tid] = s1g[b * NN + g * SRCB + tid];
  }

  // ---- segment descriptors + block scan ----
  if (tid < 256) {
    int lo = offsT[g * 256 + tid];
    int hi = (g == 255) ? 1024 : offsT[(g + 1) * 256 + tid];
    srcPos[tid] = tid * 1024 + lo;
    dstBase[tid] = hi - lo;                    // temp: len
  }
  __syncthreads();
  if (tid < 64) {
    int i0 = tid * 4;
    int c0 = dstBase[i0], c1 = dstBase[i0 + 1], c2 = dstBase[i0 + 2], c3 = dstBase[i0 + 3];
    int sum = c0 + c1 + c2 + c3;
    int x = sum;
#pragma unroll
    for (int off = 1; off < 64; off <<= 1) {
      int y = __shfl_up(x, off, 64);
      if (tid >= off) x += y;
    }
    int ex = x - sum;
    dstBase[i0] = ex; dstBase[i0 + 1] = ex + c0;
    dstBase[i0 + 2] = ex + c0 + c1; dstBase[i0 + 3] = ex + c0 + c1 + c2;
    if (tid == 63) dstBase[256] = x;           // total
  }
  __syncthreads();
  int T = dstBase[256]; if (T > BCAP) T = BCAP;

  // ---- merge + per-edge value + rank ----
  unsigned mpk[2]; float mv[2]; int msl[2], mrk[2]; bool mok[2];
#pragma unroll
  for (int j = 0; j < 2; ++j) {
    int i = tid + j * 1024;
    mok[j] = (i < T);
    mpk[j] = 0; mv[j] = 0.f; msl[j] = 0; mrk[j] = 0;
    if (mok[j]) {
      int lo = 0, hi = 255;                    // binary search: dstBase[c] <= i
#pragma unroll
      for (int st = 0; st < 8; ++st) {
        int mid = (lo + hi + 1) >> 1;
        if (dstBase[mid] <= i) lo = mid; else hi = mid - 1;
      }
      int c = lo, jj = i - dstBase[c];
      uint2 E = coarse[srcPos[c] + jj];
      float wgt = cew[srcPos[c] + jj];
      int dst = (int)(E.x & 0x1FFFu);
      int src = (int)E.y;
      float x = s1loc[src & (SRCB - 1)] + s2b[dst];
      float val = (x > 0.f ? x : ALPHA * x) * wgt;
      mpk[j] = E.x; mv[j] = val; msl[j] = src & (SRCB - 1);
      mrk[j] = atomicAdd(&rhist[msl[j]], 1);
    }
  }
  __syncthreads();
  if (tid < SRCB) {                            // exclusive scan of 32 counts
    int c = rhist[tid];
    int x = c;
#pragma unroll
    for (int off = 1; off < SRCB; off <<= 1) {
      int y = __shfl_up(x, off, 64);
      if (tid >= off) x += y;
    }
    roffs[tid] = x - c;
  }
  __syncthreads();
#pragma unroll
  for (int j = 0; j < 2; ++j)
    if (mok[j]) grp[roffs[msl[j]] + mrk[j]] = make_uint2(mpk[j], __float_as_uint(mv[j]));
  __syncthreads();

  const float* Whb = Wh + (size_t)b * NN * FDIM;
  unsigned* mywords = bmap + w * 256;
  int fg = lane & 15, es = lane >> 4;
  for (int q = 0; q < 2; ++q) {
    int slo = w * 2 + q;                       // src-in-bucket [0,32)
    int beg = roffs[slo];
    int deg = rhist[slo];
    int n = g * SRCB + slo;
    float4 r4 = make_float4(0.f, 0.f, 0.f, 0.f);
    if (deg > 0) {
      float inv;
      if (deg <= 64) {
        unsigned k0 = 0; float v0 = 0.f;
        if (lane < deg) { uint2 E = grp[beg + lane]; k0 = E.x; v0 = __uint_as_float(E.y); }
        // ---- bitmap dup detect: fastpath skips the O(deg) shuffle loop ----
#pragma unroll
        for (int u = 0; u < 4; ++u) mywords[u * 64 + lane] = 0u;
        bool dup = false;
        if (lane < deg) {
          int dst = (int)(k0 & 0x1FFFu);
          unsigned old = atomicOr(&mywords[dst >> 5], 1u << (dst & 31));
          dup = (old >> (dst & 31)) & 1u;
        }
        if (__ballot(dup) != 0ull) {           // ~13% of rows
          for (int j = 0; j < deg; ++j) {
            unsigned q2 = __shfl(k0, j, 64);
            if ((((q2 ^ k0) & 0x1FFFu) == 0u) & (q2 > k0)) v0 = 0.f;   // dup loser
          }
        }
        float m = (v0 != 0.f) ? v0 : -INFINITY;
#pragma unroll
        for (int off = 32; off; off >>= 1) m = fmaxf(m, __shfl_xor(m, off, 64));
        float p = (v0 != 0.f) ? expf(v0 - m) : 0.f;
        float sum = p;
#pragma unroll
        for (int off = 32; off; off >>= 1) sum += __shfl_xor(sum, off, 64);
        inv = (sum > 0.f) ? 1.f / sum : 0.f;
        if (lane < deg) grp[beg + lane].y = __float_as_uint(p);
      } else {                                 // deg in (64,128] — vanishingly rare
        int dg = deg > ROWCAP ? ROWCAP : deg;
        deg = dg;
        unsigned k0 = 0, k1 = 0; float v0 = 0.f, v1 = 0.f;
        { uint2 E = grp[beg + lane]; k0 = E.x; v0 = __uint_as_float(E.y); }
        if (lane + 64 < dg) { uint2 E = grp[beg + lane + 64]; k1 = E.x; v1 = __uint_as_float(E.y); }
        for (int j = 0; j < 64; ++j) {
          unsigned q2 = __shfl(k0, j, 64);
          if ((((q2 ^ k0) & 0x1FFFu) == 0u) & (q2 > k0)) v0 = 0.f;
          if ((((q2 ^ k1) & 0x1FFFu) == 0u) & (q2 > k1)) v1 = 0.f;
        }
        for (int j = 0; j < dg - 64; ++j) {
          unsigned q2 = __shfl(k1, j, 64);
          if ((((q2 ^ k0) & 0x1FFFu) == 0u) & (q2 > k0)) v0 = 0.f;
          if ((((q2 ^ k1) & 0x1FFFu) == 0u) & (q2 > k1)) v1 = 0.f;
        }
        float m = fmaxf((v0 != 0.f) ? v0 : -INFINITY, (v1 != 0.f) ? v1 : -INFINITY);
#pragma unroll
        for (int off = 32; off; off >>= 1) m = fmaxf(m, __shfl_xor(m, off, 64));
        float p0 = (v0 != 0.f) ? expf(v0 - m) : 0.f;
        float p1 = (v1 != 0.f) ? expf(v1 - m) : 0.f;
        float sum = p0 + p1;
#pragma unroll
        for (int off = 32; off; off >>= 1) sum += __shfl_xor(sum, off, 64);
        inv = (sum > 0.f) ? 1.f / sum : 0.f;
        grp[beg + lane].y = __float_as_uint(p0);
        if (lane + 64 < dg) grp[beg + lane + 64].y = __float_as_uint(p1);
      }
      // 4-lane-per-edge gather: 8 float4 loads in flight (covers 32 edges)
      float4 acc = make_float4(0.f, 0.f, 0.f, 0.f);
      for (int kk = 0; kk < deg; kk += 32) {
        float4 vv[8]; float pp[8];
#pragma unroll
        for (int u = 0; u < 8; ++u) {
          int k = kk + u * 4 + es;
          int kc = k < deg ? k : deg - 1;      // clamp: stays a valid entry
          uint2 E = grp[beg + kc];
          pp[u] = (k < deg) ? __uint_as_float(E.y) : 0.f;
          vv[u] = *((const float4*)(Whb + (E.x & 0x1FFFu) * 64) + fg);
        }
#pragma unroll
        for (int u = 0; u < 8; ++u) {
          acc.x += pp[u] * vv[u].x; acc.y += pp[u] * vv[u].y;
          acc.z += pp[u] * vv[u].z; acc.w += pp[u] * vv[u].w;
        }
      }
#pragma unroll
      for (int off = 16; off <= 32; off <<= 1) {
        acc.x += __shfl_xor(acc.x, off, 64);
        acc.y += __shfl_xor(acc.y, off, 64);
        acc.z += __shfl_xor(acc.z, off, 64);
        acc.w += __shfl_xor(acc.w, off, 64);
      }
      r4.x = acc.x * inv; r4.y = acc.y * inv; r4.z = acc.z * inv; r4.w = acc.w * inv;
    }
    if (es == 0) {                             // lanes 0..15 store 64 floats
      r4.x = r4.x > 0.f ? r4.x : expm1f(r4.x);
      r4.y = r4.y > 0.f ? r4.y : expm1f(r4.y);
      r4.z = r4.z > 0.f ? r4.z : expm1f(r4.z);
      r4.w = r4.w > 0.f ? r4.w : expm1f(r4.w);
      *((float4*)(out + ((size_t)b * NN + n) * 64) + fg) = r4;
    }
  }
}

extern "C" void kernel_launch(void* const* d_in, const int* in_sizes, int n_in,
                              void* d_out, int out_size, void* d_ws, size_t ws_size,
                              hipStream_t stream) {
  const float* h  = (const float*)d_in[0];
  const float* W  = (const float*)d_in[1];
  const float* a  = (const float*)d_in[2];
  const int*   ei = (const int*)d_in[3];
  const float* ew = (const float*)d_in[4];
  float* out = (float*)d_out;

  char* ws = (char*)d_ws;
  float*          Wh     = (float*)(ws + OFF_WH);
  float*          s1     = (float*)(ws + OFF_S1);
  float*          s2     = (float*)(ws + OFF_S2);
  unsigned short* offsT  = (unsigned short*)(ws + OFF_OFFS);
  uint2*          coarse = (uint2*)(ws + OFF_CRS);
  float*          cew    = (float*)(ws + OFF_CEW);

  stage1_kernel<<<256, 512, 0, stream>>>(h, W, a, ei, ew, Wh, s1, s2, offsT, coarse, cew);
  stage2_kernel<<<BATCH * NB, 1024, 0, stream>>>(s1, s2, offsT, coarse, cew, Wh, out);
}

// Round 12
// 100.933 us; speedup vs baseline: 1.6963x; 1.6963x over previous
//
#include <hip/hip_runtime.h>
#include <hip/hip_bf16.h>
#include <math.h>

#define NN     8192
#define FDIM   64
#define EDGES  262144
#define BATCH  2
#define ALPHA  0.2f

#define NB     256        // coarse buckets (src >> 5)
#define SRCB   32         // srcs per bucket
#define BCAP   1280       // mean 1024 + 8 sigma
#define ROWCAP 128        // per-src cap (Poisson(32): P(>128) negligible)

// ---- ws layout ----
#define OFF_WH    0u          // float[B*N*64]  4 MB
#define OFF_S1    4194304u    // float[B*N]     64 KB
#define OFF_S2    4259840u    // float[B*N]     64 KB
#define OFF_OFFS  4325376u    // u16[256][256]  128 KB  (offsT[g][chunk])
#define OFF_CRS   4456448u    // uint2[256*1024] 2 MB (chunk-private, bucket-sorted)
#define OFF_CEW   6553600u    // float[256*1024] 1 MB (edge weights, same order)

// K1: R7's proven stage1 (1024 thr, LDS-staged GEMM, 4 rows/wave, no spill)
// + one addition: permute ew into bucket order (cew) during the scatter.
__global__ __launch_bounds__(1024) void stage1_kernel(
    const float* __restrict__ h, const float* __restrict__ W,
    const float* __restrict__ a, const int* __restrict__ ei,
    const float* __restrict__ ew,
    float* __restrict__ Wh, float* __restrict__ s1g, float* __restrict__ s2g,
    unsigned short* __restrict__ offsT, uint2* __restrict__ coarse,
    float* __restrict__ cew) {
  __shared__ float sW[64 * 65];   // pad: bank (lane+k)%32, 2-way = free
  __shared__ float sH[64 * 64];
  __shared__ int hist[NB];
  __shared__ int offs[NB];
  int tid = threadIdx.x, lane = tid & 63, w = tid >> 6;
  int blk = blockIdx.x;

  // ---- bucket: hist + rank (LDS only) ----
  int e = blk * 1024 + tid;
  int s = ei[e], d = ei[EDGES + e];
  int g = s >> 5;
  if (tid < NB) hist[tid] = 0;
  __syncthreads();
  int rank = atomicAdd(&hist[g], 1);
  __syncthreads();
  if (tid < 64) {                             // wave 0: exclusive scan of 256
    int i0 = tid * 4;
    int c0 = hist[i0], c1 = hist[i0 + 1], c2 = hist[i0 + 2], c3 = hist[i0 + 3];
    int sum = c0 + c1 + c2 + c3;
    int x = sum;
#pragma unroll
    for (int off = 1; off < 64; off <<= 1) {
      int y = __shfl_up(x, off, 64);
      if (tid >= off) x += y;
    }
    int ex = x - sum;
    offs[i0] = ex; offs[i0 + 1] = ex + c0;
    offs[i0 + 2] = ex + c0 + c1; offs[i0 + 3] = ex + c0 + c1 + c2;
  }
  __syncthreads();
  float wgt = ew[e];                          // coalesced
  int pos = blk * 1024 + offs[g] + rank;
  coarse[pos] = make_uint2(((unsigned)e << 13) | (unsigned)d, (unsigned)s);
  cew[pos] = wgt;
  if (tid < NB) offsT[tid * 256 + blk] = (unsigned short)offs[tid];

  // ---- prep: Wh = h@W^T, s1, s2 (64 rows per block, LDS-staged) ----
  for (int i = tid; i < 4096; i += 1024) sW[(i >> 6) * 65 + (i & 63)] = W[i];
  int rr = lane >> 4, c4 = lane & 15;
  int nn0 = blk * 64 + w * 4;                 // [0, B*N)
  *(float4*)(sH + (w * 4 + rr) * 64 + c4 * 4) =
      *(const float4*)(h + (size_t)(nn0 + rr) * 64 + c4 * 4);
  __syncthreads();

  const float* wp = sW + lane * 65;
  const float* hp = sH + (w * 4) * 64;
  float acc[4] = {0.f, 0.f, 0.f, 0.f};
#pragma unroll 8
  for (int k = 0; k < 64; ++k) {
    float wv = wp[k];
    acc[0] += hp[k] * wv;
    acc[1] += hp[64 + k] * wv;
    acc[2] += hp[128 + k] * wv;
    acc[3] += hp[192 + k] * wv;
  }
  float a1 = a[lane], a2 = a[64 + lane];
#pragma unroll
  for (int r = 0; r < 4; ++r) {
    int nn = nn0 + r;
    Wh[(size_t)nn * 64 + lane] = acc[r];
    float p1 = acc[r] * a1, p2 = acc[r] * a2;
#pragma unroll
    for (int off = 32; off; off >>= 1) {
      p1 += __shfl_xor(p1, off, 64);
      p2 += __shfl_xor(p2, off, 64);
    }
    if (lane == 0) { s1g[nn] = p1; s2g[nn] = p2; }
  }
}

// K2: 512 blocks (B x NB) x 1024 thr. Merge 256 chunk segments, regroup by
// src in LDS, then per wave x2 rows: bitmap dup-detect (fastpath skips the
// O(deg) shuffle dedupe), masked softmax, 4-lane-per-edge float4 gather.
__global__ __launch_bounds__(1024) void stage2_kernel(
    const float* __restrict__ s1g, const float* __restrict__ s2g,
    const unsigned short* __restrict__ offsT, const uint2* __restrict__ coarse,
    const float* __restrict__ cew, const float* __restrict__ Wh,
    float* __restrict__ out) {
  __shared__ uint2 grp[BCAP];
  __shared__ int dstBase[257];
  __shared__ int srcPos[256];
  __shared__ int rhist[SRCB];
  __shared__ int roffs[SRCB];
  __shared__ float s1loc[SRCB];
  __shared__ unsigned bmap[16 * 256];          // per-wave 8192-bit dst bitmap
  int tid = threadIdx.x, lane = tid & 63, w = tid >> 6;   // 16 waves
  int blk = blockIdx.x;
  int xcd = blk & 7;
  int b = xcd >> 2;                            // XCD 0-3: batch 0, 4-7: batch 1
  int g = (blk >> 3) * 4 + (xcd & 3);          // [0, 256)
  const float* s2b = s2g + b * NN;
  if (tid < SRCB) {
    rhist[tid] = 0;
    s1loc[tid] = s1g[b * NN + g * SRCB + tid];
  }

  // ---- segment descriptors + block scan ----
  if (tid < 256) {
    int lo = offsT[g * 256 + tid];
    int hi = (g == 255) ? 1024 : offsT[(g + 1) * 256 + tid];
    srcPos[tid] = tid * 1024 + lo;
    dstBase[tid] = hi - lo;                    // temp: len
  }
  __syncthreads();
  if (tid < 64) {
    int i0 = tid * 4;
    int c0 = dstBase[i0], c1 = dstBase[i0 + 1], c2 = dstBase[i0 + 2], c3 = dstBase[i0 + 3];
    int sum = c0 + c1 + c2 + c3;
    int x = sum;
#pragma unroll
    for (int off = 1; off < 64; off <<= 1) {
      int y = __shfl_up(x, off, 64);
      if (tid >= off) x += y;
    }
    int ex = x - sum;
    dstBase[i0] = ex; dstBase[i0 + 1] = ex + c0;
    dstBase[i0 + 2] = ex + c0 + c1; dstBase[i0 + 3] = ex + c0 + c1 + c2;
    if (tid == 63) dstBase[256] = x;           // total
  }
  __syncthreads();
  int T = dstBase[256]; if (T > BCAP) T = BCAP;

  // ---- merge + per-edge value + rank ----
  unsigned mpk[2]; float mv[2]; int msl[2], mrk[2]; bool mok[2];
#pragma unroll
  for (int j = 0; j < 2; ++j) {
    int i = tid + j * 1024;
    mok[j] = (i < T);
    mpk[j] = 0; mv[j] = 0.f; msl[j] = 0; mrk[j] = 0;
    if (mok[j]) {
      int lo = 0, hi = 255;                    // binary search: dstBase[c] <= i
#pragma unroll
      for (int st = 0; st < 8; ++st) {
        int mid = (lo + hi + 1) >> 1;
        if (dstBase[mid] <= i) lo = mid; else hi = mid - 1;
      }
      int c = lo, jj = i - dstBase[c];
      uint2 E = coarse[srcPos[c] + jj];
      float wgt = cew[srcPos[c] + jj];
      int dst = (int)(E.x & 0x1FFFu);
      int src = (int)E.y;
      float x = s1loc[src & (SRCB - 1)] + s2b[dst];
      float val = (x > 0.f ? x : ALPHA * x) * wgt;
      mpk[j] = E.x; mv[j] = val; msl[j] = src & (SRCB - 1);
      mrk[j] = atomicAdd(&rhist[msl[j]], 1);
    }
  }
  __syncthreads();
  if (tid < SRCB) {                            // exclusive scan of 32 counts
    int c = rhist[tid];
    int x = c;
#pragma unroll
    for (int off = 1; off < SRCB; off <<= 1) {
      int y = __shfl_up(x, off, 64);
      if (tid >= off) x += y;
    }
    roffs[tid] = x - c;
  }
  __syncthreads();
#pragma unroll
  for (int j = 0; j < 2; ++j)
    if (mok[j]) grp[roffs[msl[j]] + mrk[j]] = make_uint2(mpk[j], __float_as_uint(mv[j]));
  __syncthreads();

  const float* Whb = Wh + (size_t)b * NN * FDIM;
  unsigned* mywords = bmap + w * 256;
  int fg = lane & 15, es = lane >> 4;
  for (int q = 0; q < 2; ++q) {
    int slo = w * 2 + q;                       // src-in-bucket [0,32)
    int beg = roffs[slo];
    int deg = rhist[slo];
    int n = g * SRCB + slo;
    float4 r4 = make_float4(0.f, 0.f, 0.f, 0.f);
    if (deg > 0) {
      float inv;
      if (deg <= 64) {
        unsigned k0 = 0; float v0 = 0.f;
        if (lane < deg) { uint2 E = grp[beg + lane]; k0 = E.x; v0 = __uint_as_float(E.y); }
        // ---- bitmap dup detect: fastpath skips the O(deg) shuffle loop ----
#pragma unroll
        for (int u = 0; u < 4; ++u) mywords[u * 64 + lane] = 0u;
        bool dup = false;
        if (lane < deg) {
          int dst = (int)(k0 & 0x1FFFu);
          unsigned old = atomicOr(&mywords[dst >> 5], 1u << (dst & 31));
          dup = (old >> (dst & 31)) & 1u;
        }
        if (__ballot(dup) != 0ull) {           // ~13% of rows
          for (int j = 0; j < deg; ++j) {
            unsigned q2 = __shfl(k0, j, 64);
            if ((((q2 ^ k0) & 0x1FFFu) == 0u) & (q2 > k0)) v0 = 0.f;   // dup loser
          }
        }
        float m = (v0 != 0.f) ? v0 : -INFINITY;
#pragma unroll
        for (int off = 32; off; off >>= 1) m = fmaxf(m, __shfl_xor(m, off, 64));
        float p = (v0 != 0.f) ? expf(v0 - m) : 0.f;
        float sum = p;
#pragma unroll
        for (int off = 32; off; off >>= 1) sum += __shfl_xor(sum, off, 64);
        inv = (sum > 0.f) ? 1.f / sum : 0.f;
        if (lane < deg) grp[beg + lane].y = __float_as_uint(p);
      } else {                                 // deg in (64,128] — vanishingly rare
        int dg = deg > ROWCAP ? ROWCAP : deg;
        deg = dg;
        unsigned k0 = 0, k1 = 0; float v0 = 0.f, v1 = 0.f;
        { uint2 E = grp[beg + lane]; k0 = E.x; v0 = __uint_as_float(E.y); }
        if (lane + 64 < dg) { uint2 E = grp[beg + lane + 64]; k1 = E.x; v1 = __uint_as_float(E.y); }
        for (int j = 0; j < 64; ++j) {
          unsigned q2 = __shfl(k0, j, 64);
          if ((((q2 ^ k0) & 0x1FFFu) == 0u) & (q2 > k0)) v0 = 0.f;
          if ((((q2 ^ k1) & 0x1FFFu) == 0u) & (q2 > k1)) v1 = 0.f;
        }
        for (int j = 0; j < dg - 64; ++j) {
          unsigned q2 = __shfl(k1, j, 64);
          if ((((q2 ^ k0) & 0x1FFFu) == 0u) & (q2 > k0)) v0 = 0.f;
          if ((((q2 ^ k1) & 0x1FFFu) == 0u) & (q2 > k1)) v1 = 0.f;
        }
        float m = fmaxf((v0 != 0.f) ? v0 : -INFINITY, (v1 != 0.f) ? v1 : -INFINITY);
#pragma unroll
        for (int off = 32; off; off >>= 1) m = fmaxf(m, __shfl_xor(m, off, 64));
        float p0 = (v0 != 0.f) ? expf(v0 - m) : 0.f;
        float p1 = (v1 != 0.f) ? expf(v1 - m) : 0.f;
        float sum = p0 + p1;
#pragma unroll
        for (int off = 32; off; off >>= 1) sum += __shfl_xor(sum, off, 64);
        inv = (sum > 0.f) ? 1.f / sum : 0.f;
        grp[beg + lane].y = __float_as_uint(p0);
        if (lane + 64 < dg) grp[beg + lane + 64].y = __float_as_uint(p1);
      }
      // 4-lane-per-edge gather: 8 float4 loads in flight (covers 32 edges)
      float4 acc = make_float4(0.f, 0.f, 0.f, 0.f);
      for (int kk = 0; kk < deg; kk += 32) {
        float4 vv[8]; float pp[8];
#pragma unroll
        for (int u = 0; u < 8; ++u) {
          int k = kk + u * 4 + es;
          int kc = k < deg ? k : deg - 1;      // clamp: stays a valid entry
          uint2 E = grp[beg + kc];
          pp[u] = (k < deg) ? __uint_as_float(E.y) : 0.f;
          vv[u] = *((const float4*)(Whb + (E.x & 0x1FFFu) * 64) + fg);
        }
#pragma unroll
        for (int u = 0; u < 8; ++u) {
          acc.x += pp[u] * vv[u].x; acc.y += pp[u] * vv[u].y;
          acc.z += pp[u] * vv[u].z; acc.w += pp[u] * vv[u].w;
        }
      }
#pragma unroll
      for (int off = 16; off <= 32; off <<= 1) {
        acc.x += __shfl_xor(acc.x, off, 64);
        acc.y += __shfl_xor(acc.y, off, 64);
        acc.z += __shfl_xor(acc.z, off, 64);
        acc.w += __shfl_xor(acc.w, off, 64);
      }
      r4.x = acc.x * inv; r4.y = acc.y * inv; r4.z = acc.z * inv; r4.w = acc.w * inv;
    }
    if (es == 0) {                             // lanes 0..15 store 64 floats
      r4.x = r4.x > 0.f ? r4.x : expm1f(r4.x);
      r4.y = r4.y > 0.f ? r4.y : expm1f(r4.y);
      r4.z = r4.z > 0.f ? r4.z : expm1f(r4.z);
      r4.w = r4.w > 0.f ? r4.w : expm1f(r4.w);
      *((float4*)(out + ((size_t)b * NN + n) * 64) + fg) = r4;
    }
  }
}

extern "C" void kernel_launch(void* const* d_in, const int* in_sizes, int n_in,
                              void* d_out, int out_size, void* d_ws, size_t ws_size,
                              hipStream_t stream) {
  const float* h  = (const float*)d_in[0];
  const float* W  = (const float*)d_in[1];
  const float* a  = (const float*)d_in[2];
  const int*   ei = (const int*)d_in[3];
  const float* ew = (const float*)d_in[4];
  float* out = (float*)d_out;

  char* ws = (char*)d_ws;
  float*          Wh     = (float*)(ws + OFF_WH);
  float*          s1     = (float*)(ws + OFF_S1);
  float*          s2     = (float*)(ws + OFF_S2);
  unsigned short* offsT  = (unsigned short*)(ws + OFF_OFFS);
  uint2*          coarse = (uint2*)(ws + OFF_CRS);
  float*          cew    = (float*)(ws + OFF_CEW);

  stage1_kernel<<<256, 1024, 0, stream>>>(h, W, a, ei, ew, Wh, s1, s2, offsT, coarse, cew);
  stage2_kernel<<<BATCH * NB, 1024, 0, stream>>>(s1, s2, offsT, coarse, cew, Wh, out);
}